// Round 4
// baseline (702.038 us; speedup 1.0000x reference)
//
#include <hip/hip_runtime.h>
#include <hip/hip_bf16.h>

// Problem constants
#define T_DIM 64
#define B_DIM 512
#define D_DIM 1536
#define H_DIM 1024
#define M_DIM (T_DIM * B_DIM)   // 32768 rows through the MLP
#define DISCOUNT 0.997f
#define LAM 0.95f

// GEMM tiling: 256x256 C-tile, 512 threads (8 waves, 2m x 4n), BK=32.
// QUAD-buffered LDS K-tiles (4 x 32 KB = 128 KB), prefetch depth 3 tiles,
// counted vmcnt(8) at each tile boundary. NEW (R4): each tile body is split
// into 4 barrier-delimited phases (m201 8-phase pattern at BK=32 scale).
#define BM 256
#define BN 256
#define BK 32
#define TILES_M (M_DIM / BM)    // 128
#define TILES_N (H_DIM / BN)    // 4
#define N_XCD 8

typedef __bf16 bf16x8 __attribute__((ext_vector_type(8)));
typedef float  f32x4  __attribute__((ext_vector_type(4)));

__device__ __forceinline__ void async_load16(const void* g, void* l) {
    __builtin_amdgcn_global_load_lds(
        (const __attribute__((address_space(1))) void*)g,
        (__attribute__((address_space(3))) void*)l,
        16, 0, 0);
}

__device__ __forceinline__ unsigned short f2bf_raw(float f) {
    __hip_bfloat16 h = __float2bfloat16(f);
    return *reinterpret_cast<unsigned short*>(&h);
}

// ---------------------------------------------------------------------------
// feat fp32 -> bf16, vectorized (float4 in, ushort4 out)
// ---------------------------------------------------------------------------
__global__ __launch_bounds__(256) void cvt_bf16_kernel(
    const float* __restrict__ x, __hip_bfloat16* __restrict__ y, long n4) {
    long i = (long)blockIdx.x * blockDim.x + threadIdx.x;
    if (i >= n4) return;
    float4 v = reinterpret_cast<const float4*>(x)[i];
    ushort4 o;
    o.x = f2bf_raw(v.x);
    o.y = f2bf_raw(v.y);
    o.z = f2bf_raw(v.z);
    o.w = f2bf_raw(v.w);
    reinterpret_cast<ushort4*>(y)[i] = o;
}

// ---------------------------------------------------------------------------
// All 4 weight transposes in one launch. W (K x N fp32) -> Wt (N x K bf16).
// ---------------------------------------------------------------------------
__global__ __launch_bounds__(256) void transpose_cvt_all_kernel(
    const float* __restrict__ W0, const float* __restrict__ W1,
    const float* __restrict__ W2, const float* __restrict__ W3,
    __hip_bfloat16* __restrict__ T0, __hip_bfloat16* __restrict__ T1,
    __hip_bfloat16* __restrict__ T2, __hip_bfloat16* __restrict__ T3) {
    __shared__ float tile[32][33];
    int z = blockIdx.z;
    const float* W;
    __hip_bfloat16* Tt;
    int K;
    if (z == 0)      { W = W0; Tt = T0; K = D_DIM; }
    else if (z == 1) { W = W1; Tt = T1; K = H_DIM; }
    else if (z == 2) { W = W2; Tt = T2; K = H_DIM; }
    else             { W = W3; Tt = T3; K = H_DIM; }
    int k0 = blockIdx.x * 32, n0 = blockIdx.y * 32;
    if (k0 >= K) return;
    int tx = threadIdx.x, ty = threadIdx.y;  // 32 x 8
    #pragma unroll
    for (int r = ty; r < 32; r += 8)
        tile[r][tx] = W[(size_t)(k0 + r) * H_DIM + n0 + tx];
    __syncthreads();
    #pragma unroll
    for (int r = ty; r < 32; r += 8)
        Tt[(size_t)(n0 + r) * K + k0 + tx] = __float2bfloat16(tile[tx][r]);
}

// ---------------------------------------------------------------------------
// C[m][n] = silu( sum_k A[m][k] * Bt[n][k] + bias[n] ), output bf16.
//
// R3 measured 4900 cyc/K-tile vs 1030 cyc MFMA floor + ~860 cyc LDS port:
// ~75% stall from a monolithic 1-barrier body (reads-burst then MFMA-burst,
// no phase overlap). R4 keeps R3's verified dataflow (quad-buffer depth-3,
// vmcnt(8)/4/0, granule swizzle, C^T epilogue) and splits each tile into
// FOUR barrier-delimited phases:
//   {stage 1 gload of tile t+3; ds_read one C-quadrant; s_barrier;
//    lgkmcnt(0)+sched_barrier(0); setprio(1); 8 MFMA; setprio(0)}
// Quadrant order Q(m0,n0),Q(m0,n1),Q(m1,n1),Q(m1,n0): per-phase reads
// 6/2/4/2 (only a 2-read B re-read). Reads of phase p+1 issue during phase
// p's MFMA pipe drain; stages trickle 1/phase. 5 barriers/tile = m201's
// barrier rate (its measured 62% MfmaUtil regime). One counted vmcnt per
// tile at the top; never drains to 0 mid-loop (T4).
//
// Swizzle (verified 0 conflicts in R3): granule = 4*(row&1) +
// (colgrp ^ ((row>>1)&3)); staging source column uses the same permutation.
// ---------------------------------------------------------------------------
__global__ __launch_bounds__(512, 2) void gemm_silu_kernel(
    const __hip_bfloat16* __restrict__ A,
    const __hip_bfloat16* __restrict__ Bt,
    const float* __restrict__ bias,
    __hip_bfloat16* __restrict__ C,
    int K) {

    __shared__ alignas(16) __hip_bfloat16 lds[65536];   // 128 KB

    const int tid  = threadIdx.x;
    const int wave = tid >> 6;         // 0..7
    const int lane = tid & 63;
    const int quad = lane >> 4;        // 0..3 (k-slice of fragment)
    const int r16  = lane & 15;        // 0..15
    const int wm   = wave & 1;         // wave row in 2x4
    const int wn   = wave >> 1;        // wave col in 2x4 (0..3)

    // XCD-aware tile assignment: 512 blocks = 128 M-tiles x 4 N-tiles
    const int l     = blockIdx.x;
    const int xcd   = l & (N_XCD - 1);
    const int local = l >> 3;                    // 0..63
    const int tn    = local & (TILES_N - 1);     // 0..3
    const int tm    = (xcd << 4) | (local >> 2); // 0..127
    const int m0 = tm * BM;
    const int n0 = tn * BN;

    // --- staging geometry: one global_load_lds covers 16 rows x 32 cols.
    // lane -> row lane>>2, col group lane&3. Source col pre-swizzled with
    // s(row) = (row>>1)&3.
    const int rsub = lane >> 2;                       // 0..15
    const int cgrp = lane & 3;                        // 0..3
    const int scol = ((cgrp ^ ((rsub >> 1) & 3)) << 3);
    const __hip_bfloat16* gA = A  + (size_t)(m0 + wave * 32 + rsub) * K + scol;
    const __hip_bfloat16* gB = Bt + (size_t)(n0 + wave * 32 + rsub) * K + scol;
    const int ldsOf0 = (wave * 32) * 32;              // elems within a buf
    const int ldsOf1 = (wave * 32 + 16) * 32;

    // --- fragment read offsets (elems within a buf), swizzled to match
    const int swz    = ((quad ^ ((r16 >> 1) & 3)) << 3);
    const int rdoffA = (wm * 128 + r16) * 32 + swz;
    const int rdoffB = (wn * 64  + r16) * 32 + swz;

    f32x4 acc[8][4];
    #pragma unroll
    for (int i = 0; i < 8; ++i)
        #pragma unroll
        for (int j = 0; j < 4; ++j)
            acc[i][j] = (f32x4){0.f, 0.f, 0.f, 0.f};

// stage one of the 4 gloads (w = 0:A-lo 1:A-hi 2:B-lo 3:B-hi) of tile tt
#define STAGE1(tt, w) do { \
        const int sbb_ = (tt) & 3; \
        const size_t ko_ = (size_t)(tt) * BK; \
        if ((w) == 0) async_load16(gA + ko_,                  &lds[sbb_ * 8192] + ldsOf0); \
        if ((w) == 1) async_load16(gA + ko_ + (size_t)16 * K, &lds[sbb_ * 8192] + ldsOf1); \
        if ((w) == 2) async_load16(gB + ko_,                  &lds[32768 + sbb_ * 8192] + ldsOf0); \
        if ((w) == 3) async_load16(gB + ko_ + (size_t)16 * K, &lds[32768 + sbb_ * 8192] + ldsOf1); \
    } while (0)

#define RD_A(i) (*reinterpret_cast<const bf16x8*>(Ab + rdoffA + (i) * 512))
#define RD_B(j) (*reinterpret_cast<const bf16x8*>(Bb + rdoffB + (j) * 512))

// C^T accumulation: mfma(B-frag, A-frag) -> lane&15 = m, regs = n.
// Quadrant (mq, nq): i in 0..3 (m-blocks mq*4+i), j in 0..1 (n-blocks nq*2+j)
#define MMQ(mq, nq, AF, BF) do { \
        _Pragma("unroll") \
        for (int ii = 0; ii < 4; ++ii) { \
            acc[(mq)*4+ii][(nq)*2+0] = __builtin_amdgcn_mfma_f32_16x16x32_bf16( \
                BF[0], AF[ii], acc[(mq)*4+ii][(nq)*2+0], 0, 0, 0); \
            acc[(mq)*4+ii][(nq)*2+1] = __builtin_amdgcn_mfma_f32_16x16x32_bf16( \
                BF[1], AF[ii], acc[(mq)*4+ii][(nq)*2+1], 0, 0, 0); \
        } \
    } while (0)

#define PHASE_SYNC() do { \
        __builtin_amdgcn_s_barrier(); \
        asm volatile("s_waitcnt lgkmcnt(0)" ::: "memory"); \
        __builtin_amdgcn_sched_barrier(0); \
    } while (0)

#define BODY(t, VMCNT, DOSTAGE) do { \
        asm volatile("s_waitcnt vmcnt(" #VMCNT ")" ::: "memory"); \
        __builtin_amdgcn_s_barrier(); \
        __builtin_amdgcn_sched_barrier(0); \
        const int bb = (t) & 3; \
        const __hip_bfloat16* Ab = &lds[bb * 8192]; \
        const __hip_bfloat16* Bb = &lds[32768 + bb * 8192]; \
        bf16x8 aLo[4], aHi[4], bLo[2], bHi[2]; \
        /* P1: stage A-lo(t+3); read Q(m0,n0) */ \
        if (DOSTAGE) STAGE1((t) + 3, 0); \
        bLo[0] = RD_B(0); bLo[1] = RD_B(1); \
        aLo[0] = RD_A(0); aLo[1] = RD_A(1); aLo[2] = RD_A(2); aLo[3] = RD_A(3); \
        PHASE_SYNC(); \
        __builtin_amdgcn_s_setprio(1); MMQ(0, 0, aLo, bLo); __builtin_amdgcn_s_setprio(0); \
        /* P2: stage A-hi; read B(n1) */ \
        if (DOSTAGE) STAGE1((t) + 3, 1); \
        bHi[0] = RD_B(2); bHi[1] = RD_B(3); \
        PHASE_SYNC(); \
        __builtin_amdgcn_s_setprio(1); MMQ(0, 1, aLo, bHi); __builtin_amdgcn_s_setprio(0); \
        /* P3: stage B-lo; read A(m1) */ \
        if (DOSTAGE) STAGE1((t) + 3, 2); \
        aHi[0] = RD_A(4); aHi[1] = RD_A(5); aHi[2] = RD_A(6); aHi[3] = RD_A(7); \
        PHASE_SYNC(); \
        __builtin_amdgcn_s_setprio(1); MMQ(1, 1, aHi, bHi); __builtin_amdgcn_s_setprio(0); \
        /* P4: stage B-hi; re-read B(n0) */ \
        if (DOSTAGE) STAGE1((t) + 3, 3); \
        bLo[0] = RD_B(0); bLo[1] = RD_B(1); \
        PHASE_SYNC(); \
        __builtin_amdgcn_s_setprio(1); MMQ(1, 0, aHi, bLo); __builtin_amdgcn_s_setprio(0); \
    } while (0)

    // prologue: stage tiles 0..2 (12 wave-instrs outstanding)
    #pragma unroll
    for (int pt = 0; pt < 3; ++pt) {
        STAGE1(pt, 0); STAGE1(pt, 1); STAGE1(pt, 2); STAGE1(pt, 3);
    }

    const int NT = K / BK;   // 48 or 32
    for (int t = 0; t < NT - 2; ++t)
        BODY(t, 8, (t + 3 < NT));
    BODY(NT - 2, 4, false);
    BODY(NT - 1, 0, false);

#undef STAGE1
#undef RD_A
#undef RD_B
#undef MMQ
#undef PHASE_SYNC
#undef BODY

    // epilogue: bias + SiLU + packed 8-B stores.
    // C^T fragment layout: m = lane&15 (block i), n = j*16 + quad*4 + rr.
    #pragma unroll
    for (int j = 0; j < 4; ++j) {
        const int c0 = n0 + wn * 64 + j * 16 + quad * 4;
        const float4 b4 = *reinterpret_cast<const float4*>(&bias[c0]);
        const float* bp = reinterpret_cast<const float*>(&b4);
        #pragma unroll
        for (int i = 0; i < 8; ++i) {
            const int row = m0 + wm * 128 + i * 16 + r16;
            ushort4 o;
            unsigned short* op = reinterpret_cast<unsigned short*>(&o);
            #pragma unroll
            for (int rr = 0; rr < 4; ++rr) {
                const float v = acc[i][j][rr] + bp[rr];
                const float s = v / (1.f + __expf(-v));
                op[rr] = f2bf_raw(s);
            }
            *reinterpret_cast<ushort4*>(&C[(size_t)row * H_DIM + c0]) = o;
        }
    }
}

// ---------------------------------------------------------------------------
// value[m] = sum_n H[m][n] * Wo[n] + bo      (N = 1024 fixed; 1 wave / row)
// ---------------------------------------------------------------------------
__global__ __launch_bounds__(256) void gemv_value_kernel(
    const __hip_bfloat16* __restrict__ H,
    const float* __restrict__ Wo,
    const float* __restrict__ bo_p,
    float* __restrict__ value, int M) {
    int wave = threadIdx.x >> 6, lane = threadIdx.x & 63;
    int row = blockIdx.x * 4 + wave;
    if (row >= M) return;
    const __hip_bfloat16* hrow = H + (size_t)row * H_DIM;
    float sum = 0.f;
    #pragma unroll
    for (int half = 0; half < 2; ++half) {
        int col = half * 512 + lane * 8;
        uint4 raw = *reinterpret_cast<const uint4*>(hrow + col);
        const __hip_bfloat16* hp = reinterpret_cast<const __hip_bfloat16*>(&raw);
        #pragma unroll
        for (int e = 0; e < 8; ++e)
            sum += __bfloat162float(hp[e]) * Wo[col + e];
    }
    #pragma unroll
    for (int off = 32; off > 0; off >>= 1)
        sum += __shfl_down(sum, off, 64);
    if (lane == 0) value[row] = sum + bo_p[0];
}

// ---------------------------------------------------------------------------
// GAE backward scan. value: (T,B) fp32. out: ret (63x512) then baseline.
// ---------------------------------------------------------------------------
__global__ __launch_bounds__(64) void gae_kernel(
    const float* __restrict__ value,
    const float* __restrict__ reward,
    const float* __restrict__ cont,
    float* __restrict__ out) {
    int b = blockIdx.x * blockDim.x + threadIdx.x;
    if (b >= B_DIM) return;
    float adv = 0.f;
    float v_next = value[(T_DIM - 1) * B_DIM + b];
    for (int t = T_DIM - 2; t >= 0; --t) {
        float v_t  = value[t * B_DIM + b];
        float disc = cont[(t + 1) * B_DIM + b] * DISCOUNT;
        float delta = reward[t * B_DIM + b] + disc * v_next - v_t;
        adv = delta + disc * LAM * adv;
        out[t * B_DIM + b] = adv + v_t;                           // ret
        out[(T_DIM - 1) * B_DIM + t * B_DIM + b] = v_t;           // baseline
        v_next = v_t;
    }
}

// ---------------------------------------------------------------------------
extern "C" void kernel_launch(void* const* d_in, const int* in_sizes, int n_in,
                              void* d_out, int out_size, void* d_ws, size_t ws_size,
                              hipStream_t stream) {
    const float* feat   = (const float*)d_in[0];
    const float* reward = (const float*)d_in[1];
    const float* cont   = (const float*)d_in[2];
    const float* W[4]   = {(const float*)d_in[3], (const float*)d_in[5],
                           (const float*)d_in[7], (const float*)d_in[9]};
    const float* bias[4] = {(const float*)d_in[4], (const float*)d_in[6],
                            (const float*)d_in[8], (const float*)d_in[10]};
    const float* Wo = (const float*)d_in[11];
    const float* bo = (const float*)d_in[12];
    float* out = (float*)d_out;

    // workspace layout
    char* ws = (char*)d_ws;
    __hip_bfloat16* Xb = (__hip_bfloat16*)ws; ws += (size_t)M_DIM * D_DIM * 2;   // 96 MB
    __hip_bfloat16* Ha = (__hip_bfloat16*)ws; ws += (size_t)M_DIM * H_DIM * 2;   // 64 MB
    __hip_bfloat16* Hb = (__hip_bfloat16*)ws; ws += (size_t)M_DIM * H_DIM * 2;   // 64 MB
    __hip_bfloat16* Wt0 = (__hip_bfloat16*)ws; ws += (size_t)H_DIM * D_DIM * 2;  // 3 MB
    __hip_bfloat16* Wt1 = (__hip_bfloat16*)ws; ws += (size_t)H_DIM * H_DIM * 2;
    __hip_bfloat16* Wt2 = (__hip_bfloat16*)ws; ws += (size_t)H_DIM * H_DIM * 2;
    __hip_bfloat16* Wt3 = (__hip_bfloat16*)ws; ws += (size_t)H_DIM * H_DIM * 2;
    float* value = (float*)ws; ws += (size_t)M_DIM * 4;

    // 1. feat -> bf16
    long n4 = (long)M_DIM * D_DIM / 4;
    cvt_bf16_kernel<<<(int)((n4 + 255) / 256), 256, 0, stream>>>(feat, Xb, n4);

    // 2. all weight transposes, one launch
    transpose_cvt_all_kernel<<<dim3(D_DIM / 32, H_DIM / 32, 4), dim3(32, 8), 0, stream>>>(
        W[0], W[1], W[2], W[3], Wt0, Wt1, Wt2, Wt3);

    // 3. MLP: 4 GEMM + SiLU layers (1D grid, XCD-swizzled inside)
    const int nblocks = TILES_M * TILES_N;  // 512
    gemm_silu_kernel<<<nblocks, 512, 0, stream>>>(Xb, Wt0, bias[0], Ha, D_DIM);
    gemm_silu_kernel<<<nblocks, 512, 0, stream>>>(Ha, Wt1, bias[1], Hb, H_DIM);
    gemm_silu_kernel<<<nblocks, 512, 0, stream>>>(Hb, Wt2, bias[2], Ha, H_DIM);
    gemm_silu_kernel<<<nblocks, 512, 0, stream>>>(Ha, Wt3, bias[3], Hb, H_DIM);

    // 4. value head GEMV
    gemv_value_kernel<<<M_DIM / 4, 256, 0, stream>>>(Hb, Wo, bo, value, M_DIM);

    // 5. GAE scan
    gae_kernel<<<8, 64, 0, stream>>>(value, reward, cont, out);
}